// Round 15
// baseline (121.541 us; speedup 1.0000x reference)
//
#include <hip/hip_runtime.h>
#include <hip/hip_bf16.h>

#define L_SEQ    1024
#define IN_DIM   256
#define DIM_MSA  32
#define PAIR_DIM 64

typedef float f4 __attribute__((ext_vector_type(4)));
typedef float f2 __attribute__((ext_vector_type(2)));
typedef short s8 __attribute__((ext_vector_type(8)));

__device__ __forceinline__ unsigned short f2bf(float f) {
    unsigned u = __float_as_uint(f);
    u = (u + 0x7FFFu + ((u >> 16) & 1u)) >> 16;   // RNE
    return (unsigned short)u;
}

// s[i][c] = b1[c] + sum_d seq[i][d] * W1[c][d]  (fp32 + bf16 copies)
__global__ void k_proj1(const float* __restrict__ seq, const float* __restrict__ W1,
                        const float* __restrict__ b1, float* __restrict__ s,
                        unsigned short* __restrict__ s_bf) {
    int t = blockIdx.x * blockDim.x + threadIdx.x;   // 1024*32 threads
    int i = t >> 5, c = t & 31;
    const float4* sq = (const float4*)(seq + i * IN_DIM);
    const float4* w  = (const float4*)(W1  + c * IN_DIM);
    float a0 = 0.f, a1 = 0.f, a2 = 0.f, a3 = 0.f;
#pragma unroll
    for (int d4 = 0; d4 < IN_DIM / 4; ++d4) {
        float4 x = sq[d4], y = w[d4];
        a0 += x.x * y.x;  a1 += x.y * y.y;
        a2 += x.z * y.z;  a3 += x.w * y.w;
    }
    float v = b1[c] + ((a0 + a1) + (a2 + a3));
    s[t]    = v;
    s_bf[t] = f2bf(v);
}

// tmp_bf[jp][d] = bf16( sum_c s[j][c] * W2[p][c*32+d] ), jp = j*64+p
__global__ void k_proj2(const float* __restrict__ s, const float* __restrict__ W2,
                        unsigned short* __restrict__ tmp_bf) {
    int t = blockIdx.x * blockDim.x + threadIdx.x;   // 1024*64*8 threads
    int q = t & 7, p = (t >> 3) & 63, j = t >> 9;
    const float4* w  = (const float4*)W2;            // idx = p*256 + c*8 + q
    const float*  sj = s + j * DIM_MSA;
    float4 acc = {0.f, 0.f, 0.f, 0.f};
#pragma unroll
    for (int c = 0; c < DIM_MSA; ++c) {
        float  sc = sj[c];
        float4 wv = w[p * 256 + c * 8 + q];
        acc.x += sc * wv.x;  acc.y += sc * wv.y;
        acc.z += sc * wv.z;  acc.w += sc * wv.w;
    }
    ushort4 o;
    o.x = f2bf(acc.x);  o.y = f2bf(acc.y);
    o.z = f2bf(acc.z);  o.w = f2bf(acc.w);
    ((ushort4*)tmp_bf)[t] = o;   // shorts 4t..4t+3 == [jp][d] row-major
}

// out[i][jp] = MFMA(s_bf, tmp_bf) + b2 + pair; LDS-transposed epilogue.
// vs R14: 16 tiles split into TWO passes of 8 -> wave slab 8KB, block LDS
// 32KB -> 5 blocks/CU (was 2). C-store columns XOR-swizzled by kg*16:
// 4-way bank conflict -> 2-way (free). Phase-2 f2 streams (512B/instr).
// A/B/C lane mapping identical to R13/R14 (HW-verified, absmax 0.0625).
__global__ __launch_bounds__(256) void k_outer_mfma3(
    const unsigned short* __restrict__ s_bf, const unsigned short* __restrict__ tmp_bf,
    const float* __restrict__ pair, const float* __restrict__ b2,
    float* __restrict__ out) {
    __shared__ float lds[4 * 16 * 128];          // 32 KB (4 waves x 8 KB)
    int tid = threadIdx.x;
    int w = tid >> 6, l = tid & 63;
    int n = l & 15, kg = l >> 4;
    int jb = blockIdx.x & 63;                    // jp-block fast axis
    int it = blockIdx.x >> 6;                    // i-tile

    // A-frag: s_bf[it*16 + n][kg*8 .. +7]
    s8 a = *(const s8*)(s_bf + (size_t)(it * 16 + n) * DIM_MSA + kg * 8);

    int jp0 = jb * 1024 + w * 256;               // wave's 256 jp
    float* slab = lds + w * 2048;                // wave-private 8 KB

    f2 bias = *(const f2*)(b2 + ((2 * l) & 63));
    size_t rowbase = (size_t)(it * 16) * 65536 + (size_t)jp0 + 2 * l;

#pragma unroll
    for (int P = 0; P < 2; ++P) {
        // ---- phase 1: 8 MFMA tiles -> swizzled LDS [16 i][128 jp] ----
        const unsigned short* bp =
            tmp_bf + (size_t)(jp0 + P * 128 + n) * DIM_MSA + kg * 8;
#pragma unroll
        for (int t = 0; t < 8; ++t) {
            s8 b = *(const s8*)(bp + (size_t)t * 16 * DIM_MSA);  // 1KB/wave, L2
            f4 z = {0.f, 0.f, 0.f, 0.f};
            f4 c = __builtin_amdgcn_mfma_f32_16x16x32_bf16(a, b, z, 0, 0, 0);
            // C: reg r -> i_loc = kg*4 + r, jp_loc = t*16 + n
            // phys col = jp_loc ^ (kg*16)  => 2-way banks on store
            float* dst = slab + (kg * 4) * 128 + ((t ^ kg) * 16) + n;
            dst[0]   = c.x;
            dst[128] = c.y;
            dst[256] = c.z;
            dst[384] = c.w;
        }
        // same-wave RAW via lgkmcnt; no barrier (wave-private slab)

        // ---- phase 2: stream 16 i-rows x 128 jp (f2 = 512B/instr) ----
        const float* pp = pair + rowbase + P * 128;
        float*       op = out  + rowbase + P * 128;
#pragma unroll 8
        for (int i = 0; i < 16; ++i) {
            int colphys = (2 * l) ^ (((i >> 2) & 3) << 4);       // unswizzle
            f2 cc = *(const f2*)(slab + i * 128 + colphys);
            f2 pv = *(const f2*)(pp + (size_t)i * 65536);
            f2 o  = cc + bias + pv;
            __builtin_nontemporal_store(o, (f2*)(op + (size_t)i * 65536));
        }
    }
}

extern "C" void kernel_launch(void* const* d_in, const int* in_sizes, int n_in,
                              void* d_out, int out_size, void* d_ws, size_t ws_size,
                              hipStream_t stream) {
    const float* seq  = (const float*)d_in[0];   // [1,1024,256]
    const float* pair = (const float*)d_in[1];   // [1,1024,1024,64]
    const float* W1   = (const float*)d_in[2];   // [32,256]
    const float* b1   = (const float*)d_in[3];   // [32]
    const float* W2   = (const float*)d_in[4];   // [64,1024]
    const float* b2   = (const float*)d_in[5];   // [64]
    float* out = (float*)d_out;

    float*          s_ws = (float*)d_ws;                     // 128 KB fp32
    unsigned short* sbf  = (unsigned short*)(s_ws + 32768);  // 64 KB bf16
    unsigned short* tbf  = sbf + 32768;                      // 4 MB bf16 [jp][d]

    k_proj1<<<(L_SEQ * DIM_MSA) / 256, 256, 0, stream>>>(seq, W1, b1, s_ws, sbf);
    k_proj2<<<(L_SEQ * PAIR_DIM * (DIM_MSA / 4)) / 256, 256, 0, stream>>>(s_ws, W2, tbf);
    k_outer_mfma3<<<64 * 64, 256, 0, stream>>>(sbf, tbf, pair, b2, out);
}

// Round 16
// 114.174 us; speedup vs baseline: 1.0645x; 1.0645x over previous
//
#include <hip/hip_runtime.h>
#include <hip/hip_bf16.h>

#define L_SEQ    1024
#define IN_DIM   256
#define DIM_MSA  32
#define PAIR_DIM 64

typedef float f4 __attribute__((ext_vector_type(4)));
typedef short s8 __attribute__((ext_vector_type(8)));

__device__ __forceinline__ unsigned short f2bf(float f) {
    unsigned u = __float_as_uint(f);
    u = (u + 0x7FFFu + ((u >> 16) & 1u)) >> 16;   // RNE
    return (unsigned short)u;
}

// s[i][c] = b1[c] + sum_d seq[i][d] * W1[c][d]  (fp32 + bf16 copies)
__global__ void k_proj1(const float* __restrict__ seq, const float* __restrict__ W1,
                        const float* __restrict__ b1, float* __restrict__ s,
                        unsigned short* __restrict__ s_bf) {
    int t = blockIdx.x * blockDim.x + threadIdx.x;   // 1024*32 threads
    int i = t >> 5, c = t & 31;
    const float4* sq = (const float4*)(seq + i * IN_DIM);
    const float4* w  = (const float4*)(W1  + c * IN_DIM);
    float a0 = 0.f, a1 = 0.f, a2 = 0.f, a3 = 0.f;
#pragma unroll
    for (int d4 = 0; d4 < IN_DIM / 4; ++d4) {
        float4 x = sq[d4], y = w[d4];
        a0 += x.x * y.x;  a1 += x.y * y.y;
        a2 += x.z * y.z;  a3 += x.w * y.w;
    }
    float v = b1[c] + ((a0 + a1) + (a2 + a3));
    s[t]    = v;
    s_bf[t] = f2bf(v);
}

// tmp_bf[jp][d] = bf16( sum_c s[j][c] * W2[p][c*32+d] ), jp = j*64+p
__global__ void k_proj2(const float* __restrict__ s, const float* __restrict__ W2,
                        unsigned short* __restrict__ tmp_bf) {
    int t = blockIdx.x * blockDim.x + threadIdx.x;   // 1024*64*8 threads
    int q = t & 7, p = (t >> 3) & 63, j = t >> 9;
    const float4* w  = (const float4*)W2;            // idx = p*256 + c*8 + q
    const float*  sj = s + j * DIM_MSA;
    float4 acc = {0.f, 0.f, 0.f, 0.f};
#pragma unroll
    for (int c = 0; c < DIM_MSA; ++c) {
        float  sc = sj[c];
        float4 wv = w[p * 256 + c * 8 + q];
        acc.x += sc * wv.x;  acc.y += sc * wv.y;
        acc.z += sc * wv.z;  acc.w += sc * wv.w;
    }
    ushort4 o;
    o.x = f2bf(acc.x);  o.y = f2bf(acc.y);
    o.z = f2bf(acc.z);  o.w = f2bf(acc.w);
    ((ushort4*)tmp_bf)[t] = o;   // shorts 4t..4t+3 == [jp][d] row-major
}

// out[i][jp] = MFMA(s_bf, tmp_bf) + b2 + pair; LDS-transposed epilogue.
// R14 structure (16 tiles, 16KB wave slab, f4 1KB/instr streams) + pair
// prefetch overlapping the MFMA phase + nt loads for pair (protect tmp in L2).
// launch_bounds(256,2): LDS caps us at 2 blocks/CU regardless, so let the
// allocator keep 16 prefetched f4s + frags resident (VGPR budget 256).
__global__ __launch_bounds__(256, 2) void k_outer_mfma2(
    const unsigned short* __restrict__ s_bf, const unsigned short* __restrict__ tmp_bf,
    const float* __restrict__ pair, const float* __restrict__ b2,
    float* __restrict__ out) {
    __shared__ float lds[4 * 16 * 256];          // 64 KB
    int tid = threadIdx.x;
    int w = tid >> 6, l = tid & 63;
    int n = l & 15, kg = l >> 4;
    int jb = blockIdx.x & 63;                    // jp-block fast axis
    int it = blockIdx.x >> 6;                    // i-tile

    // A-frag: s_bf[it*16 + n][kg*8 .. +7]
    s8 a = *(const s8*)(s_bf + (size_t)(it * 16 + n) * DIM_MSA + kg * 8);

    int jp0 = jb * 1024 + w * 256;               // wave's jp range
    const unsigned short* bp = tmp_bf + (size_t)(jp0 + n) * DIM_MSA + kg * 8;
    float* myl = lds + w * 4096;                 // wave-private 16 KB

    f4 b4 = *(const f4*)(b2 + ((l * 4) & 63));
    size_t rowbase = (size_t)(it * 16) * 65536 + (size_t)jp0 + l * 4;
    const float* pp = pair + rowbase;
    float*       op = out  + rowbase;

    // ---- prefetch pair rows 0..7 (in flight during the MFMA phase) ----
    f4 p0 = __builtin_nontemporal_load((const f4*)(pp + 0ull * 65536));
    f4 p1 = __builtin_nontemporal_load((const f4*)(pp + 1ull * 65536));
    f4 p2 = __builtin_nontemporal_load((const f4*)(pp + 2ull * 65536));
    f4 p3 = __builtin_nontemporal_load((const f4*)(pp + 3ull * 65536));
    f4 p4 = __builtin_nontemporal_load((const f4*)(pp + 4ull * 65536));
    f4 p5 = __builtin_nontemporal_load((const f4*)(pp + 5ull * 65536));
    f4 p6 = __builtin_nontemporal_load((const f4*)(pp + 6ull * 65536));
    f4 p7 = __builtin_nontemporal_load((const f4*)(pp + 7ull * 65536));

    // ---- phase 1: 16 MFMA tiles -> LDS [16 i][256 jp] ----
#pragma unroll
    for (int t = 0; t < 16; ++t) {
        s8 b = *(const s8*)(bp + (size_t)t * 16 * DIM_MSA);  // 1KB/wave, L2
        f4 z = {0.f, 0.f, 0.f, 0.f};
        f4 c = __builtin_amdgcn_mfma_f32_16x16x32_bf16(a, b, z, 0, 0, 0);
        // C: reg r -> i_loc = kg*4 + r, jp_loc = t*16 + n
        float* dst = myl + (kg * 4) * 256 + t * 16 + n;
        dst[0]   = c.x;
        dst[256] = c.y;
        dst[512] = c.z;
        dst[768] = c.w;
    }
    // same-wave RAW through LDS: compiler inserts lgkmcnt wait; no barrier.

    // ---- issue pair rows 8..15, then stream ----
    f4 q0 = __builtin_nontemporal_load((const f4*)(pp +  8ull * 65536));
    f4 q1 = __builtin_nontemporal_load((const f4*)(pp +  9ull * 65536));
    f4 q2 = __builtin_nontemporal_load((const f4*)(pp + 10ull * 65536));
    f4 q3 = __builtin_nontemporal_load((const f4*)(pp + 11ull * 65536));
    f4 q4 = __builtin_nontemporal_load((const f4*)(pp + 12ull * 65536));
    f4 q5 = __builtin_nontemporal_load((const f4*)(pp + 13ull * 65536));
    f4 q6 = __builtin_nontemporal_load((const f4*)(pp + 14ull * 65536));
    f4 q7 = __builtin_nontemporal_load((const f4*)(pp + 15ull * 65536));

#define ROW(I, PV) do {                                                       \
        f4 cc = *(const f4*)(myl + (I) * 256 + l * 4);                        \
        __builtin_nontemporal_store(cc + b4 + (PV),                           \
                                    (f4*)(op + (size_t)(I) * 65536));         \
    } while (0)

    ROW(0, p0);  ROW(1, p1);  ROW(2, p2);  ROW(3, p3);
    ROW(4, p4);  ROW(5, p5);  ROW(6, p6);  ROW(7, p7);
    ROW(8, q0);  ROW(9, q1);  ROW(10, q2); ROW(11, q3);
    ROW(12, q4); ROW(13, q5); ROW(14, q6); ROW(15, q7);
#undef ROW
}

extern "C" void kernel_launch(void* const* d_in, const int* in_sizes, int n_in,
                              void* d_out, int out_size, void* d_ws, size_t ws_size,
                              hipStream_t stream) {
    const float* seq  = (const float*)d_in[0];   // [1,1024,256]
    const float* pair = (const float*)d_in[1];   // [1,1024,1024,64]
    const float* W1   = (const float*)d_in[2];   // [32,256]
    const float* b1   = (const float*)d_in[3];   // [32]
    const float* W2   = (const float*)d_in[4];   // [64,1024]
    const float* b2   = (const float*)d_in[5];   // [64]
    float* out = (float*)d_out;

    float*          s_ws = (float*)d_ws;                     // 128 KB fp32
    unsigned short* sbf  = (unsigned short*)(s_ws + 32768);  // 64 KB bf16
    unsigned short* tbf  = sbf + 32768;                      // 4 MB bf16 [jp][d]

    k_proj1<<<(L_SEQ * DIM_MSA) / 256, 256, 0, stream>>>(seq, W1, b1, s_ws, sbf);
    k_proj2<<<(L_SEQ * PAIR_DIM * (DIM_MSA / 4)) / 256, 256, 0, stream>>>(s_ws, W2, tbf);
    k_outer_mfma2<<<64 * 64, 256, 0, stream>>>(sbf, tbf, pair, b2, out);
}